// Round 2
// baseline (85.775 us; speedup 1.0000x reference)
//
#include <hip/hip_runtime.h>

typedef __attribute__((ext_vector_type(4))) float f32x4;
typedef __attribute__((ext_vector_type(8))) short short8;
typedef __attribute__((ext_vector_type(8))) __bf16 bf16x8;

constexpr int kN = 4096;
constexpr int kF = 256;
constexpr int kH = 4;
constexpr int kD = 64;
constexpr float kLog2e = 1.4426950408889634f;

__device__ __forceinline__ unsigned short f2us(float x) {
  __bf16 b = (__bf16)x;
  return __builtin_bit_cast(unsigned short, b);
}

// ---------------------------------------------------------------------------
// k_wa: wa[h][i] = sum_d W[h][i][d] * a[h][d]
// ---------------------------------------------------------------------------
__global__ __launch_bounds__(256) void k_wa(const float* __restrict__ W,
                                            const float* __restrict__ a_src,
                                            const float* __restrict__ a_dst,
                                            float* __restrict__ wa_src,
                                            float* __restrict__ wa_dst) {
  const int h = blockIdx.x, i = threadIdx.x;
  __shared__ float as[kD], ad[kD];
  if (i < kD) { as[i] = a_src[h * kD + i]; ad[i] = a_dst[h * kD + i]; }
  __syncthreads();
  const float* w = W + ((size_t)h * kF + i) * kD;
  float ss = 0.f, sd = 0.f;
#pragma unroll
  for (int d = 0; d < kD; d++) { const float wv = w[d]; ss += wv * as[d]; sd += wv * ad[d]; }
  wa_src[h * kF + i] = ss;
  wa_dst[h * kF + i] = sd;
}

// ---------------------------------------------------------------------------
// k_wh: Whb[h] = bf16( h @ W[h] ) via MFMA, stored pre-swizzled in B-frag order
// frag_id = ((h*128 + mstep)*4 + dt)*64 + lane, 8 bf16/lane.
// ---------------------------------------------------------------------------
__global__ __launch_bounds__(256) void k_wh(const float* __restrict__ hmat,
                                            const float* __restrict__ W,
                                            unsigned short* __restrict__ whb) {
  const int h = blockIdx.x & 3, rb = blockIdx.x >> 2;
  const int row0 = rb * 64;
  __shared__ unsigned short wlds[16384];
  const int t = threadIdx.x;
  {
    const int d = t & 63;
    const int dt = d >> 4, dl = d & 15;
    for (int kb = 0; kb < 64; kb++) {
      const int k = kb * 4 + (t >> 6);
      const float wv = W[((size_t)h * kF + k) * kD + d];
      const int ks = k >> 5, kl = k & 31;
      const int lane2 = ((kl >> 3) << 4) | dl;
      const int e = kl & 7;
      wlds[(((ks * 4 + dt) * 64 + lane2) << 3) + e] = f2us(wv);
    }
  }
  __syncthreads();
  const int wave = t >> 6, lane = t & 63;
  const int lr = lane & 15, lg = lane >> 4;
  const int nrow = row0 + wave * 16 + lr;
  f32x4 acc[4] = {};
  const float* hrow = hmat + (size_t)nrow * kF + 8 * lg;
#pragma unroll
  for (int ks = 0; ks < 8; ks++) {
    const f32x4 h0 = *reinterpret_cast<const f32x4*>(hrow + ks * 32);
    const f32x4 h1 = *reinterpret_cast<const f32x4*>(hrow + ks * 32 + 4);
    bf16x8 af;
#pragma unroll
    for (int j = 0; j < 4; j++) { af[j] = (__bf16)h0[j]; af[4 + j] = (__bf16)h1[j]; }
#pragma unroll
    for (int dt = 0; dt < 4; dt++) {
      const short8 bs = *reinterpret_cast<const short8*>(wlds + (((ks * 4 + dt) * 64 + lane) << 3));
      acc[dt] = __builtin_amdgcn_mfma_f32_16x16x32_bf16(af, __builtin_bit_cast(bf16x8, bs), acc[dt], 0, 0, 0);
    }
  }
#pragma unroll
  for (int dt = 0; dt < 4; dt++) {
#pragma unroll
    for (int r = 0; r < 4; r++) {
      const int n = row0 + wave * 16 + lg * 4 + r;
      const int mstep = n >> 5, kl = n & 31;
      const int lane2 = ((kl >> 3) << 4) | lr;
      const int e = kl & 7;
      whb[((((size_t)(h * 128 + mstep) * 4 + dt) * 64 + lane2) << 3) + e] = f2us(acc[dt][r]);
    }
  }
}

// ---------------------------------------------------------------------------
// k_s: s_src[h][n] = h[n,:]·wa_src[h,:]  (exact fp32)
// ---------------------------------------------------------------------------
__global__ __launch_bounds__(256) void k_s(const float* __restrict__ hmat,
                                           const float* __restrict__ wa_src,
                                           const float* __restrict__ wa_dst,
                                           float* __restrict__ s_src,
                                           float* __restrict__ s_dst) {
  const int wave = threadIdx.x >> 6, lane = threadIdx.x & 63;
  const int n = blockIdx.x * 4 + wave;
  const f32x4 hv = reinterpret_cast<const f32x4*>(hmat + (size_t)n * kF)[lane];
#pragma unroll
  for (int h = 0; h < kH; h++) {
    const f32x4 sv = reinterpret_cast<const f32x4*>(wa_src + h * kF)[lane];
    const f32x4 dv = reinterpret_cast<const f32x4*>(wa_dst + h * kF)[lane];
    float as = hv[0] * sv[0] + hv[1] * sv[1] + hv[2] * sv[2] + hv[3] * sv[3];
    float ad = hv[0] * dv[0] + hv[1] * dv[1] + hv[2] * dv[2] + hv[3] * dv[3];
#pragma unroll
    for (int off = 32; off > 0; off >>= 1) {
      as += __shfl_xor(as, off);
      ad += __shfl_xor(ad, off);
    }
    if (lane == 0) { s_src[h * kN + n] = as; s_dst[h * kN + n] = ad; }
  }
}

// ---------------------------------------------------------------------------
// k_max: M[h] = max_n s_dst[h][n]
// ---------------------------------------------------------------------------
__global__ __launch_bounds__(256) void k_max(const float* __restrict__ s_dst,
                                             float* __restrict__ Mh) {
  const int h = blockIdx.x, t = threadIdx.x;
  float m = -1e30f;
  for (int n = t; n < kN; n += 256) m = fmaxf(m, s_dst[h * kN + n]);
  __shared__ float red[256];
  red[t] = m;
  __syncthreads();
#pragma unroll
  for (int s = 128; s > 0; s >>= 1) {
    if (t < s) red[t] = fmaxf(red[t], red[t + s]);
    __syncthreads();
  }
  if (t == 0) Mh[h] = red[0];
}

// ---------------------------------------------------------------------------
// k_abits: adj (fp32 0/1, 64 MB) -> bitmask (2 MB), LINEAR streaming read.
// word T covers cols [32T,32T+32) flat; bit (8k+j) of word <-> byte 4T+k bit j
// <-> flat elem 32T+8k+j.  (little-endian u32 == byte order)
// ---------------------------------------------------------------------------
__global__ __launch_bounds__(256) void k_abits(const float* __restrict__ adj,
                                               unsigned int* __restrict__ bits) {
  const int T = blockIdx.x * 256 + threadIdx.x;  // 524288 words
  const f32x4* in = reinterpret_cast<const f32x4*>(adj) + (size_t)T * 8;
  unsigned int w = 0;
#pragma unroll
  for (int c = 0; c < 8; c++) {
    const f32x4 v = in[c];
#pragma unroll
    for (int i = 0; i < 4; i++) w |= (v[i] != 0.0f ? 1u : 0u) << (4 * c + i);
  }
  bits[T] = w;
}

// p-generation from mask byte m (bit j <-> element j)
__device__ __forceinline__ bf16x8 make_pb(const f32x4 u0, const f32x4 u1,
                                          const f32x4 v0, const f32x4 v1,
                                          const float cc1, const float cc2,
                                          const unsigned m) {
  bf16x8 r;
#pragma unroll
  for (int j = 0; j < 4; j++) {
    const float mf = (float)((m >> j) & 1u);
    const float arg = fmaxf(u0[j] + cc1, v0[j] + cc2);
    r[j] = (__bf16)(mf * __builtin_amdgcn_exp2f(arg));
  }
#pragma unroll
  for (int j = 0; j < 4; j++) {
    const float mf = (float)((m >> (4 + j)) & 1u);
    const float arg = fmaxf(u1[j] + cc1, v1[j] + cc2);
    r[4 + j] = (__bf16)(mf * __builtin_amdgcn_exp2f(arg));
  }
  return r;
}

// ---------------------------------------------------------------------------
// k_attn: fused mask+softmax-numerator+PV.  256 blocks = 128 rowgroups x 2
// col-splits, 8 waves = 4 heads x 2 col-interleaves, BQ=32.  Mask from the
// L2-resident bitmask (2-deep prefetch); whb B-frags prefetched 1-deep.
// Partials combined via atomicAdd into accC/zC (zeroed by memsetAsync).
// ---------------------------------------------------------------------------
__global__ __launch_bounds__(512, 2) void k_attn(const unsigned char* __restrict__ bitsb,
                                                 const unsigned short* __restrict__ whb,
                                                 const float* __restrict__ s_src,
                                                 const float* __restrict__ s_dst,
                                                 const float* __restrict__ Mh,
                                                 float* __restrict__ accC,
                                                 float* __restrict__ zC) {
  const int bid = blockIdx.x;
  const int rb = bid >> 1, cs = bid & 1;
  const int row0 = rb * 32;
  const int colbase = cs * 2048;
  const int t = threadIdx.x;
  const int wave = t >> 6, lane = t & 63;
  const int h = wave & 3, q = wave >> 2;
  const int lr = lane & 15, lg = lane >> 4;

  __shared__ float sdl[4 * 2048];  // staged s_dst slice

  {
    const int base = colbase + t * 4;
#pragma unroll
    for (int hh = 0; hh < 4; hh++) {
      const f32x4 v = *reinterpret_cast<const f32x4*>(s_dst + hh * kN + base);
      *reinterpret_cast<f32x4*>(sdl + hh * 2048 + t * 4) = v;
    }
  }
  __syncthreads();

  const float M = Mh[h];
  float c1[2], c2[2];
#pragma unroll
  for (int rt = 0; rt < 2; rt++) {
    const float A = s_src[h * kN + row0 + rt * 16 + lr];
    const float xb = A + M;
    const float B = fmaxf(xb, 0.2f * xb);  // lrelu at the global-max bound
    c1[rt] = (A - B) * kLog2e;
    c2[rt] = (0.2f * A - B) * kLog2e;
  }

  f32x4 acc[2][4] = {};
  f32x4 accz[2] = {};
  bf16x8 ones;
#pragma unroll
  for (int e = 0; e < 8; e++) ones[e] = (__bf16)1.0f;

  // mask byte addressing: byte = row*512 + col/8; per iter advance 8 bytes
  const size_t mB0 = (size_t)(row0 + lr) * 512 + ((colbase + q * 32) >> 3) + lg;
  const size_t mB1 = mB0 + (size_t)16 * 512;
  const float* sdp = sdl + h * 2048 + q * 32 + 8 * lg;
  const short8* wb = reinterpret_cast<const short8*>(whb) + (size_t)h * 32768 + lane;
  const int mstep0 = cs * 64 + q;

  // 2-deep mask prefetch
  unsigned ma0 = bitsb[mB0], ma1 = bitsb[mB1];
  unsigned mb0 = bitsb[mB0 + 8], mb1 = bitsb[mB1 + 8];
  // 1-deep B-frag prefetch
  short8 bw0, bw1, bw2, bw3;
  {
    const short8* p = wb + (size_t)mstep0 * 256;
    bw0 = p[0]; bw1 = p[64]; bw2 = p[128]; bw3 = p[192];
  }

  for (int it = 0; it < 32; it++) {
    const unsigned cm0 = ma0, cm1 = ma1;
    ma0 = mb0; ma1 = mb1;
    if (it + 2 < 32) { mb0 = bitsb[mB0 + (it + 2) * 8]; mb1 = bitsb[mB1 + (it + 2) * 8]; }

    const short8 cb0 = bw0, cb1 = bw1, cb2 = bw2, cb3 = bw3;
    if (it + 1 < 32) {
      const short8* p = wb + (size_t)(mstep0 + (it + 1) * 2) * 256;
      bw0 = p[0]; bw1 = p[64]; bw2 = p[128]; bw3 = p[192];
    }

    const float* sp = sdp + it * 64;
    const f32x4 sd0 = *reinterpret_cast<const f32x4*>(sp);
    const f32x4 sd1 = *reinterpret_cast<const f32x4*>(sp + 4);
    const f32x4 u0 = sd0 * kLog2e, u1 = sd1 * kLog2e;
    const f32x4 v0 = sd0 * (0.2f * kLog2e), v1 = sd1 * (0.2f * kLog2e);

    const bf16x8 P0 = make_pb(u0, u1, v0, v1, c1[0], c2[0], cm0);
    const bf16x8 P1 = make_pb(u0, u1, v0, v1, c1[1], c2[1], cm1);
    const bf16x8 B0 = __builtin_bit_cast(bf16x8, cb0);
    const bf16x8 B1 = __builtin_bit_cast(bf16x8, cb1);
    const bf16x8 B2 = __builtin_bit_cast(bf16x8, cb2);
    const bf16x8 B3 = __builtin_bit_cast(bf16x8, cb3);

    acc[0][0] = __builtin_amdgcn_mfma_f32_16x16x32_bf16(P0, B0, acc[0][0], 0, 0, 0);
    acc[0][1] = __builtin_amdgcn_mfma_f32_16x16x32_bf16(P0, B1, acc[0][1], 0, 0, 0);
    acc[0][2] = __builtin_amdgcn_mfma_f32_16x16x32_bf16(P0, B2, acc[0][2], 0, 0, 0);
    acc[0][3] = __builtin_amdgcn_mfma_f32_16x16x32_bf16(P0, B3, acc[0][3], 0, 0, 0);
    accz[0]   = __builtin_amdgcn_mfma_f32_16x16x32_bf16(P0, ones, accz[0], 0, 0, 0);
    acc[1][0] = __builtin_amdgcn_mfma_f32_16x16x32_bf16(P1, B0, acc[1][0], 0, 0, 0);
    acc[1][1] = __builtin_amdgcn_mfma_f32_16x16x32_bf16(P1, B1, acc[1][1], 0, 0, 0);
    acc[1][2] = __builtin_amdgcn_mfma_f32_16x16x32_bf16(P1, B2, acc[1][2], 0, 0, 0);
    acc[1][3] = __builtin_amdgcn_mfma_f32_16x16x32_bf16(P1, B3, acc[1][3], 0, 0, 0);
    accz[1]   = __builtin_amdgcn_mfma_f32_16x16x32_bf16(P1, ones, accz[1], 0, 0, 0);
  }

  // epilogue: atomic combine (2 writers per address: cs=0,1)
#pragma unroll
  for (int rt = 0; rt < 2; rt++) {
#pragma unroll
    for (int dt = 0; dt < 4; dt++)
#pragma unroll
      for (int r = 0; r < 4; r++) {
        const int n = row0 + rt * 16 + lg * 4 + r;
        const int d = dt * 16 + lr;
        atomicAdd(&accC[((size_t)h * kN + n) * kD + d], acc[rt][dt][r]);
      }
    if (lr == 0) {
#pragma unroll
      for (int r = 0; r < 4; r++)
        atomicAdd(&zC[(size_t)h * kN + row0 + rt * 16 + lg * 4 + r], accz[rt][r]);
    }
  }
}

// ---------------------------------------------------------------------------
// k_fin: out[n][h*64+d] = elu( accC / zC )
// ---------------------------------------------------------------------------
__global__ __launch_bounds__(256) void k_fin(const float* __restrict__ accC,
                                             const float* __restrict__ zC,
                                             float* __restrict__ out) {
  const int idx = blockIdx.x * 256 + threadIdx.x;  // 262144 float4s
  const int d4 = idx & 15;
  const int hh = (idx >> 4) & 3;
  const int n = idx >> 6;
  const f32x4 v = reinterpret_cast<const f32x4*>(accC)[((size_t)hh * kN + n) * 16 + d4];
  const float z = zC[hh * kN + n];
  const float rz = 1.0f / z;
  f32x4 o;
#pragma unroll
  for (int j = 0; j < 4; j++) {
    const float x = v[j] * rz;
    o[j] = x > 0.0f ? x : (__builtin_amdgcn_exp2f(x * kLog2e) - 1.0f);
  }
  reinterpret_cast<f32x4*>(out)[(size_t)n * 64 + hh * 16 + d4] = o;
}

extern "C" void kernel_launch(void* const* d_in, const int* in_sizes, int n_in,
                              void* d_out, int out_size, void* d_ws, size_t ws_size,
                              hipStream_t stream) {
  const float* hmat  = (const float*)d_in[0];
  const float* adj   = (const float*)d_in[1];
  const float* W     = (const float*)d_in[2];
  const float* a_src = (const float*)d_in[3];
  const float* a_dst = (const float*)d_in[4];
  float* out = (float*)d_out;

  char* ws = (char*)d_ws;
  unsigned short* whb = (unsigned short*)(ws);             // 2 MB   @0
  float* wa_src = (float*)(ws + 0x200000);                 // 4 KB
  float* wa_dst = (float*)(ws + 0x201000);                 // 4 KB
  float* s_src  = (float*)(ws + 0x202000);                 // 64 KB
  float* s_dst  = (float*)(ws + 0x212000);                 // 64 KB
  float* Mh     = (float*)(ws + 0x222000);                 // 16 B
  unsigned int* bits = (unsigned int*)(ws + 0x240000);     // 2 MB   @2.25M
  float* accC   = (float*)(ws + 0x440000);                 // 4 MB   @4.25M
  float* zC     = (float*)(ws + 0x840000);                 // 64 KB  @8.25M

  hipMemsetAsync(ws + 0x440000, 0, 0x410000, stream);  // zero accC+zC
  hipLaunchKernelGGL(k_wa, dim3(4), dim3(256), 0, stream, W, a_src, a_dst, wa_src, wa_dst);
  hipLaunchKernelGGL(k_wh, dim3(256), dim3(256), 0, stream, hmat, W, whb);
  hipLaunchKernelGGL(k_s, dim3(1024), dim3(256), 0, stream, hmat, wa_src, wa_dst, s_src, s_dst);
  hipLaunchKernelGGL(k_max, dim3(4), dim3(256), 0, stream, s_dst, Mh);
  hipLaunchKernelGGL(k_abits, dim3(2048), dim3(256), 0, stream, adj, bits);
  hipLaunchKernelGGL(k_attn, dim3(256), dim3(512), 0, stream,
                     (const unsigned char*)bits, whb, s_src, s_dst, Mh, accC, zC);
  hipLaunchKernelGGL(k_fin, dim3(1024), dim3(256), 0, stream, accC, zC, out);
}